// Round 1
// baseline (190.839 us; speedup 1.0000x reference)
//
#include <hip/hip_runtime.h>

#define IMG   512
#define NIMG  48                    // 16 batches * 3 channels
#define PLANE (IMG * IMG)           // 262144
#define OUTCH ((size_t)NIMG * PLANE)// floats per output tensor: 12582912
#define NTHREADS (NIMG * 64 * 64)   // one thread per 8x8 block: 196608

// Orthonormal 8-point DCT-II matrix: D[k][t]
// row 0 = sqrt(1/8); row k = 0.5*cos(pi*k*(2t+1)/16)
__device__ constexpr float Dm[8][8] = {
  { 0.3535533905932738f, 0.3535533905932738f, 0.3535533905932738f, 0.3535533905932738f,
    0.3535533905932738f, 0.3535533905932738f, 0.3535533905932738f, 0.3535533905932738f},
  { 0.4903926402016152f, 0.4157348061512726f, 0.2777851165098011f, 0.0975451610080642f,
   -0.0975451610080642f,-0.2777851165098011f,-0.4157348061512726f,-0.4903926402016152f},
  { 0.4619397662556434f, 0.1913417161825449f,-0.1913417161825449f,-0.4619397662556434f,
   -0.4619397662556434f,-0.1913417161825449f, 0.1913417161825449f, 0.4619397662556434f},
  { 0.4157348061512726f,-0.0975451610080642f,-0.4903926402016152f,-0.2777851165098011f,
    0.2777851165098011f, 0.4903926402016152f, 0.0975451610080642f,-0.4157348061512726f},
  { 0.3535533905932738f,-0.3535533905932738f,-0.3535533905932738f, 0.3535533905932738f,
    0.3535533905932738f,-0.3535533905932738f,-0.3535533905932738f, 0.3535533905932738f},
  { 0.2777851165098011f,-0.4903926402016152f, 0.0975451610080642f, 0.4157348061512726f,
   -0.4157348061512726f,-0.0975451610080642f, 0.4903926402016152f,-0.2777851165098011f},
  { 0.1913417161825449f,-0.4619397662556434f, 0.4619397662556434f,-0.1913417161825449f,
   -0.1913417161825449f, 0.4619397662556434f,-0.4619397662556434f, 0.1913417161825449f},
  { 0.0975451610080642f,-0.2777851165098011f, 0.4157348061512726f,-0.4903926402016152f,
    0.4903926402016152f,-0.4157348061512726f, 0.2777851165098011f,-0.0975451610080642f},
};

// Standard 8x8 zigzag order (verified against the reference _zigzag())
__device__ constexpr int ZZ[8][8] = {
  {  0,  1,  5,  6, 14, 15, 27, 28},
  {  2,  4,  7, 13, 16, 26, 29, 42},
  {  3,  8, 12, 17, 25, 30, 41, 43},
  {  9, 11, 18, 24, 31, 40, 44, 53},
  { 10, 19, 23, 32, 39, 45, 52, 54},
  { 20, 22, 33, 38, 46, 51, 55, 60},
  { 21, 34, 37, 47, 50, 56, 59, 61},
  { 35, 36, 48, 49, 57, 58, 62, 63},
};

// Masked IDCT of one band + scaled float4 store.
// Mask (LO <= zz < HI) folds at compile time: zero-coeff FMAs are elided.
template <int LO, int HI>
__device__ __forceinline__ void idct_band_store(const float A[8][8],
                                                float* __restrict__ dst,
                                                float scale) {
  // U[m][l] = sum_k Dm[k][m] * (mask ? A[k][l] : 0)
  float U[8][8];
#pragma unroll
  for (int l = 0; l < 8; ++l) {
#pragma unroll
    for (int m = 0; m < 8; ++m) {
      float acc = 0.0f;
#pragma unroll
      for (int k = 0; k < 8; ++k) {
        if (ZZ[k][l] >= LO && ZZ[k][l] < HI) acc += Dm[k][m] * A[k][l];
      }
      U[m][l] = acc;
    }
  }
  // sp[m][n] = sum_l U[m][l] * Dm[l][n]; scale and store row-wise
#pragma unroll
  for (int m = 0; m < 8; ++m) {
    float t[8];
#pragma unroll
    for (int n = 0; n < 8; ++n) {
      float acc = 0.0f;
#pragma unroll
      for (int l = 0; l < 8; ++l) acc += U[m][l] * Dm[l][n];
      t[n] = acc * scale;
    }
    *(float4*)(dst + (size_t)m * IMG)     = make_float4(t[0], t[1], t[2], t[3]);
    *(float4*)(dst + (size_t)m * IMG + 4) = make_float4(t[4], t[5], t[6], t[7]);
  }
}

__global__ __launch_bounds__(256) void dct_decomp_kernel(
    const float* __restrict__ x, const float* __restrict__ band_scale,
    float* __restrict__ out) {
  int tid = blockIdx.x * 256 + threadIdx.x;
  if (tid >= NTHREADS) return;

  // lane-adjacent threads take horizontally adjacent 8x8 blocks -> coalesced
  int bw  = tid & 63;          // block col
  int bh  = (tid >> 6) & 63;   // block row
  int img = tid >> 12;         // b*3 + c, 0..47

  size_t base = ((size_t)img * IMG + (size_t)bh * 8) * IMG + (size_t)bw * 8;
  const float* src = x + base;

  // load 8x8 block (two float4 per row; 32B-aligned)
  float A[8][8];
#pragma unroll
  for (int r = 0; r < 8; ++r) {
    float4 v0 = *(const float4*)(src + (size_t)r * IMG);
    float4 v1 = *(const float4*)(src + (size_t)r * IMG + 4);
    A[r][0] = v0.x; A[r][1] = v0.y; A[r][2] = v0.z; A[r][3] = v0.w;
    A[r][4] = v1.x; A[r][5] = v1.y; A[r][6] = v1.z; A[r][7] = v1.w;
  }

  // forward DCT, in place: first T = X * D^T (per-row), then C = D * T (per-col)
#pragma unroll
  for (int m = 0; m < 8; ++m) {
    float t[8];
#pragma unroll
    for (int l = 0; l < 8; ++l) {
      float acc = 0.0f;
#pragma unroll
      for (int n = 0; n < 8; ++n) acc += A[m][n] * Dm[l][n];
      t[l] = acc;
    }
#pragma unroll
    for (int l = 0; l < 8; ++l) A[m][l] = t[l];
  }
#pragma unroll
  for (int l = 0; l < 8; ++l) {
    float t[8];
#pragma unroll
    for (int k = 0; k < 8; ++k) {
      float acc = 0.0f;
#pragma unroll
      for (int m = 0; m < 8; ++m) acc += Dm[k][m] * A[m][l];
      t[k] = acc;
    }
#pragma unroll
    for (int k = 0; k < 8; ++k) A[k][l] = t[k];
  }

  float s0 = band_scale[0];
  float s1 = band_scale[1];
  float s2 = band_scale[2];

  // zigzag bands: low = [0,21), mid = [21,42), high = [42,64)
  idct_band_store< 0, 21>(A, out + base,             s0);
  idct_band_store<21, 42>(A, out + OUTCH + base,     s1);
  idct_band_store<42, 64>(A, out + 2 * OUTCH + base, s2);
}

extern "C" void kernel_launch(void* const* d_in, const int* in_sizes, int n_in,
                              void* d_out, int out_size, void* d_ws, size_t ws_size,
                              hipStream_t stream) {
  const float* x          = (const float*)d_in[0];
  const float* band_scale = (const float*)d_in[1];
  float* out              = (float*)d_out;

  dim3 grid(NTHREADS / 256);  // 768 blocks
  dim3 block(256);
  dct_decomp_kernel<<<grid, block, 0, stream>>>(x, band_scale, out);
}